// Round 5
// baseline (394.471 us; speedup 1.0000x reference)
//
#include <hip/hip_runtime.h>
#include <math.h>

#define NFEAT 4096
#define M     2048
#define THREADS 256
#define ROWS_PER_WG 4

// Data-buffer swizzle: bijective on [0,2048); lane-contiguous reads stay
// conflict-free, strided Stockham writes spread across bank pairs.
#define SWZ(i) ((i) ^ (((i) >> 4) & 15))
// Twiddle-table physical swizzle: spreads multiples-of-64 gather indices.
#define TWPHYS(e) ((e) ^ (((e) >> 4) & 15))

__device__ __forceinline__ float2 cmul(float2 a, float2 b){
    return make_float2(a.x*b.x - a.y*b.y, a.x*b.y + a.y*b.x);
}
// conj(a)*b
__device__ __forceinline__ float2 cmul_conja(float2 a, float2 b){
    return make_float2(a.x*b.x + a.y*b.y, a.x*b.y - a.y*b.x);
}
__device__ __forceinline__ float2 cadd(float2 a, float2 b){ return make_float2(a.x+b.x, a.y+b.y); }
__device__ __forceinline__ float2 csub(float2 a, float2 b){ return make_float2(a.x-b.x, a.y-b.y); }

template<int SIGN>
__device__ __forceinline__ void fft4(float2& a0, float2& a1, float2& a2, float2& a3){
    float2 t0 = cadd(a0,a2), t1 = csub(a0,a2);
    float2 t2 = cadd(a1,a3), t3 = csub(a1,a3);
    float2 r3 = (SIGN < 0) ? make_float2(t3.y, -t3.x) : make_float2(-t3.y, t3.x);
    a0 = cadd(t0,t2); a2 = csub(t0,t2);
    a1 = cadd(t1,r3); a3 = csub(t1,r3);
}

template<int SIGN>
__device__ __forceinline__ void fft8(float2 v[8]){
    const float C = 0.70710678118654752440f;
    float2 e0=v[0], e1=v[2], e2=v[4], e3=v[6];
    float2 o0=v[1], o1=v[3], o2=v[5], o3=v[7];
    fft4<SIGN>(e0,e1,e2,e3);
    fft4<SIGN>(o0,o1,o2,o3);
    float2 w1 = make_float2( C, (SIGN<0) ? -C : C);
    float2 w3 = make_float2(-C, (SIGN<0) ? -C : C);
    float2 o1w = cmul(o1, w1);
    float2 o2w = (SIGN<0) ? make_float2(o2.y, -o2.x) : make_float2(-o2.y, o2.x);
    float2 o3w = cmul(o3, w3);
    v[0]=cadd(e0,o0);  v[4]=csub(e0,o0);
    v[1]=cadd(e1,o1w); v[5]=csub(e1,o1w);
    v[2]=cadd(e2,o2w); v[6]=csub(e2,o2w);
    v[3]=cadd(e3,o3w); v[7]=csub(e3,o3w);
}

// Radix-8 Stockham stage (NS in {8,64}): ONE twiddle table load per
// butterfly (even quarter-4096 index, no fixups) + power-chain cmuls.
template<int SIGN, int NS>
__device__ __forceinline__ void stage8(const float2* __restrict__ src, float2* __restrict__ dst,
                                       const float2* __restrict__ twq, int j){
    const int m  = j & (NS - 1);
    float2 v[8];
#pragma unroll
    for (int r = 0; r < 8; ++r) v[r] = src[SWZ(j + 256*r)];
    {
        // w2048^tb, tb = m*M/(8*NS)  ->  twq index 2*tb = m*M/(4*NS) < 1024
        float2 wb = twq[TWPHYS(m * (M / (NS * 4)))];
        if (SIGN > 0) wb.y = -wb.y;
        float2 w = wb;
        v[1] = cmul(v[1], w);
#pragma unroll
        for (int r = 2; r < 8; ++r){ w = cmul(w, wb); v[r] = cmul(v[r], w); }
    }
    fft8<SIGN>(v);
    const int idxD = ((j - m) << 3) + m;
#pragma unroll
    for (int r = 0; r < 8; ++r) dst[SWZ(idxD + NS*r)] = v[r];
}

// One full row: forward FFT (fused load-stage), fused spectral+inverse
// stage 1, inverse FFT (fused store-stage). X = first scratch buffer
// written this row, Y = the other; caller alternates per row parity so no
// trailing barrier is needed.
__device__ __forceinline__ void row_body(float2* __restrict__ X, float2* __restrict__ Y,
                                         const float2* __restrict__ twq,
                                         float2 (&pre)[8], const float2 (&G)[8],
                                         const float2* __restrict__ xnext,
                                         const float2* __restrict__ br2,
                                         float2* __restrict__ yr2, int t)
{
    // s1: forward radix-8 (Ns=1) on prefetched regs -> X
    {
        float2 v[8];
#pragma unroll
        for (int r = 0; r < 8; ++r) v[r] = pre[r];
        fft8<-1>(v);
        const int idxD = t << 3;
#pragma unroll
        for (int r = 0; r < 8; ++r) X[SWZ(idxD + r)] = v[r];
    }
    __syncthreads();                                   // B1
    stage8<-1,8 >(X, Y, twq, t);  __syncthreads();     // B2
    stage8<-1,64>(Y, X, twq, t);  __syncthreads();     // B3

    // s4: forward radix-4 (Ns=512): X -> Y, then prefetch next row
#pragma unroll
    for (int h = 0; h < 2; ++h){
        const int j = t + 256*h;
        float2 w1 = twq[TWPHYS(2*j)];
        float2 w2 = cmul(w1, w1);
        float2 w3 = cmul(w2, w1);
        float2 v0 = X[SWZ(j)];
        float2 v1 = cmul(X[SWZ(j +  512)], w1);
        float2 v2 = cmul(X[SWZ(j + 1024)], w2);
        float2 v3 = cmul(X[SWZ(j + 1536)], w3);
        fft4<-1>(v0,v1,v2,v3);
        Y[SWZ(j)]        = v0;
        Y[SWZ(j +  512)] = v1;
        Y[SWZ(j + 1024)] = v2;
        Y[SWZ(j + 1536)] = v3;
    }
    if (xnext){
#pragma unroll
        for (int r = 0; r < 8; ++r) pre[r] = xnext[t + 256*r];
    }
    __syncthreads();                                   // B4

    // s5: spectral (untangle, *H, mask, retangle) fused with inverse
    // radix-8 stage 1 (no twiddles): Y -> X.  All scale factors deferred
    // to the final 1/8192.
    {
        float2 v[8];
#pragma unroll
        for (int r = 0; r < 8; ++r){
            const int k  = t + 256*r;
            const int kk = (r < 4) ? k : 2048 - k;     // bin in [0,1024]
            float2 zk = Y[SWZ(kk)];
            float2 zm = Y[SWZ((2048 - kk) & 2047)];    // kk=0 aliases (overridden)
            float2 w  = twq[TWPHYS(kk & 1023)];
            float2 A  = make_float2(zk.x + zm.x, zk.y - zm.y);   // 2*A
            float2 B  = make_float2(zk.x - zm.x, zk.y + zm.y);   // 2*B
            float2 wB = cmul(w, B);
            float2 Xc = make_float2(A.x + wB.y, A.y - wB.x);     // 2*X[kk]
            float2 vr = (r < 4) ? cmul(Xc, G[r]) : cmul_conja(Xc, G[r]);
            if (t == 0){
                if (r == 0){ float Y0 = (zk.x + zk.y) * G[0].x; vr = make_float2(Y0, Y0); }
                if (r == 4){ vr = make_float2(0.f, 0.f); }       // masked Nyquist-of-half bin
            }
            v[r] = vr;
        }
        fft8<1>(v);
        const int idxD = t << 3;
#pragma unroll
        for (int r = 0; r < 8; ++r) X[SWZ(idxD + r)] = v[r];
    }
    __syncthreads();                                   // B5
    stage8<1,8 >(X, Y, twq, t);  __syncthreads();      // B6
    stage8<1,64>(Y, X, twq, t);  __syncthreads();      // B7

    // s8: inverse radix-4 (Ns=512) fused with scale + bias + store, read X
    const float inv = (1.0f/8192.0f);
#pragma unroll
    for (int h = 0; h < 2; ++h){
        const int j = t + 256*h;
        float2 w1 = twq[TWPHYS(2*j)]; w1.y = -w1.y;
        float2 w2 = cmul(w1, w1);
        float2 w3 = cmul(w2, w1);
        float2 v0 = X[SWZ(j)];
        float2 v1 = cmul(X[SWZ(j +  512)], w1);
        float2 v2 = cmul(X[SWZ(j + 1024)], w2);
        float2 v3 = cmul(X[SWZ(j + 1536)], w3);
        fft4<1>(v0,v1,v2,v3);
        float2 vv[4] = {v0,v1,v2,v3};
#pragma unroll
        for (int r = 0; r < 4; ++r){
            const int mo = j + 512*r;
            float2 b = br2[mo];
            yr2[mo] = make_float2(fmaf(vv[r].x, inv, b.x), fmaf(vv[r].y, inv, b.y));
        }
    }
    // no trailing barrier: next row's s1 writes the OTHER buffer (parity),
    // and its first same-buffer write (s2) is behind that row's B1.
}

extern "C" __global__ void __launch_bounds__(THREADS, 4)
rfft_circ_kernel(const float* __restrict__ x,
                 const float* __restrict__ Hr,
                 const float* __restrict__ Hi,
                 const float* __restrict__ bias,
                 float* __restrict__ out)
{
    __shared__ float2 bufA[M];
    __shared__ float2 bufB[M];
    __shared__ float2 twq[1024];   // e^{-2pi i k/4096}, k<1024, phys-swizzled

    const int t = threadIdx.x;
    const size_t row0 = (size_t)blockIdx.x * ROWS_PER_WG;
    const float2* xr0 = (const float2*)(x + row0 * NFEAT);

    // Prefetch row 0 BEFORE the table build (sincos hides the HBM latency)
    float2 pre[8];
#pragma unroll
    for (int r = 0; r < 8; ++r) pre[r] = xr0[t + 256*r];

    for (int i = t; i < 1024; i += THREADS){
        float s, c;
        sincosf(-6.2831853071795864769f * (float)i * (1.0f/4096.0f), &s, &c);
        twq[TWPHYS(i)] = make_float2(c, s);
    }
    __syncthreads();

    // Row-invariant spectral factors: G[r] = H*f1 (k<1024) or conj(H)*f2.
    float2 G[8];
#pragma unroll
    for (int r = 0; r < 8; ++r){
        const int k  = t + 256*r;
        const int kk = ((r < 4) ? k : 2048 - k) & 1023;
        float2 w = twq[TWPHYS(kk)];
        float2 H = make_float2(Hr[kk], Hi[kk]);
        if (r < 4) G[r] = cmul(H, make_float2(1.f + w.y, w.x));
        else       G[r] = cmul(make_float2(H.x, -H.y), make_float2(1.f - w.y, w.x));
    }
    if (t == 0){ G[0] = make_float2(2.f*Hr[0], 0.f); G[4] = make_float2(0.f, 0.f); }

    const float2* br2 = (const float2*)bias;

#pragma unroll 1
    for (int rp = 0; rp < ROWS_PER_WG; rp += 2){
        {
            const int rr = rp;
            float2* yr2 = (float2*)(out + (row0 + rr) * NFEAT);
            const float2* xn = (rr + 1 < ROWS_PER_WG) ? xr0 + (size_t)(rr+1)*(NFEAT/2) : nullptr;
            row_body(bufA, bufB, twq, pre, G, xn, br2, yr2, t);
        }
        {
            const int rr = rp + 1;
            float2* yr2 = (float2*)(out + (row0 + rr) * NFEAT);
            const float2* xn = (rr + 1 < ROWS_PER_WG) ? xr0 + (size_t)(rr+1)*(NFEAT/2) : nullptr;
            row_body(bufB, bufA, twq, pre, G, xn, br2, yr2, t);
        }
    }
}

extern "C" void kernel_launch(void* const* d_in, const int* in_sizes, int n_in,
                              void* d_out, int out_size, void* d_ws, size_t ws_size,
                              hipStream_t stream) {
    const float* x    = (const float*)d_in[0];
    const float* Hr   = (const float*)d_in[1];
    const float* Hi   = (const float*)d_in[2];
    const float* bias = (const float*)d_in[3];
    float* out        = (float*)d_out;

    const int n_rows = in_sizes[0] / NFEAT;   // 8192 at reference shape
    dim3 grid(n_rows / ROWS_PER_WG), block(THREADS);
    hipLaunchKernelGGL(rfft_circ_kernel, grid, block, 0, stream,
                       x, Hr, Hi, bias, out);
}

// Round 6
// 251.705 us; speedup vs baseline: 1.5672x; 1.5672x over previous
//
#include <hip/hip_runtime.h>
#include <math.h>

#define NFEAT 4096
#define M     2048
#define THREADS 256
#define ROWS_PER_WG 4

// Data-buffer swizzle: bijective on [0,2048); lane-contiguous reads stay
// conflict-free, strided Stockham writes spread across bank pairs.
#define SWZ(i) ((i) ^ (((i) >> 4) & 15))
// Twiddle-table physical swizzle: spreads multiples-of-64 gather indices.
#define TWPHYS(e) ((e) ^ (((e) >> 4) & 15))

__device__ __forceinline__ float2 cmul(float2 a, float2 b){
    return make_float2(a.x*b.x - a.y*b.y, a.x*b.y + a.y*b.x);
}
// conj(a)*b
__device__ __forceinline__ float2 cmul_conja(float2 a, float2 b){
    return make_float2(a.x*b.x + a.y*b.y, a.x*b.y - a.y*b.x);
}
__device__ __forceinline__ float2 cadd(float2 a, float2 b){ return make_float2(a.x+b.x, a.y+b.y); }
__device__ __forceinline__ float2 csub(float2 a, float2 b){ return make_float2(a.x-b.x, a.y-b.y); }

template<int SIGN>
__device__ __forceinline__ void fft4(float2& a0, float2& a1, float2& a2, float2& a3){
    float2 t0 = cadd(a0,a2), t1 = csub(a0,a2);
    float2 t2 = cadd(a1,a3), t3 = csub(a1,a3);
    float2 r3 = (SIGN < 0) ? make_float2(t3.y, -t3.x) : make_float2(-t3.y, t3.x);
    a0 = cadd(t0,t2); a2 = csub(t0,t2);
    a1 = cadd(t1,r3); a3 = csub(t1,r3);
}

template<int SIGN>
__device__ __forceinline__ void fft8(float2 v[8]){
    const float C = 0.70710678118654752440f;
    float2 e0=v[0], e1=v[2], e2=v[4], e3=v[6];
    float2 o0=v[1], o1=v[3], o2=v[5], o3=v[7];
    fft4<SIGN>(e0,e1,e2,e3);
    fft4<SIGN>(o0,o1,o2,o3);
    float2 w1 = make_float2( C, (SIGN<0) ? -C : C);
    float2 w3 = make_float2(-C, (SIGN<0) ? -C : C);
    float2 o1w = cmul(o1, w1);
    float2 o2w = (SIGN<0) ? make_float2(o2.y, -o2.x) : make_float2(-o2.y, o2.x);
    float2 o3w = cmul(o3, w3);
    v[0]=cadd(e0,o0);  v[4]=csub(e0,o0);
    v[1]=cadd(e1,o1w); v[5]=csub(e1,o1w);
    v[2]=cadd(e2,o2w); v[6]=csub(e2,o2w);
    v[3]=cadd(e3,o3w); v[7]=csub(e3,o3w);
}

// Radix-8 Stockham stage (NS in {8,64}): ONE twiddle table load per
// butterfly (even quarter-4096 index, no fixups) + power-chain cmuls.
template<int SIGN, int NS>
__device__ __forceinline__ void stage8(const float2* __restrict__ src, float2* __restrict__ dst,
                                       const float2* __restrict__ twq, int j){
    const int m  = j & (NS - 1);
    float2 v[8];
#pragma unroll
    for (int r = 0; r < 8; ++r) v[r] = src[SWZ(j + 256*r)];
    {
        // w2048^tb, tb = m*M/(8*NS)  ->  twq index 2*tb = m*M/(4*NS) < 1024
        float2 wb = twq[TWPHYS(m * (M / (NS * 4)))];
        if (SIGN > 0) wb.y = -wb.y;
        float2 w = wb;
        v[1] = cmul(v[1], w);
#pragma unroll
        for (int r = 2; r < 8; ++r){ w = cmul(w, wb); v[r] = cmul(v[r], w); }
    }
    fft8<SIGN>(v);
    const int idxD = ((j - m) << 3) + m;
#pragma unroll
    for (int r = 0; r < 8; ++r) dst[SWZ(idxD + NS*r)] = v[r];
}

// One full row: forward FFT (fused load-stage), fused spectral+inverse
// stage 1, inverse FFT (fused store-stage). X = first scratch buffer
// written this row, Y = the other; caller alternates per row parity so no
// trailing barrier is needed.
__device__ __forceinline__ void row_body(float2* __restrict__ X, float2* __restrict__ Y,
                                         const float2* __restrict__ twq,
                                         float2 (&pre)[8], const float2 (&G)[8],
                                         const float2* __restrict__ xnext,
                                         const float2* __restrict__ br2,
                                         float2* __restrict__ yr2, int t)
{
    // s1: forward radix-8 (Ns=1) on prefetched regs -> X
    {
        float2 v[8];
#pragma unroll
        for (int r = 0; r < 8; ++r) v[r] = pre[r];
        fft8<-1>(v);
        const int idxD = t << 3;
#pragma unroll
        for (int r = 0; r < 8; ++r) X[SWZ(idxD + r)] = v[r];
    }
    __syncthreads();                                   // B1
    stage8<-1,8 >(X, Y, twq, t);  __syncthreads();     // B2
    stage8<-1,64>(Y, X, twq, t);  __syncthreads();     // B3

    // s4: forward radix-4 (Ns=512): X -> Y, then prefetch next row
#pragma unroll
    for (int h = 0; h < 2; ++h){
        const int j = t + 256*h;
        float2 w1 = twq[TWPHYS(2*j)];
        float2 w2 = cmul(w1, w1);
        float2 w3 = cmul(w2, w1);
        float2 v0 = X[SWZ(j)];
        float2 v1 = cmul(X[SWZ(j +  512)], w1);
        float2 v2 = cmul(X[SWZ(j + 1024)], w2);
        float2 v3 = cmul(X[SWZ(j + 1536)], w3);
        fft4<-1>(v0,v1,v2,v3);
        Y[SWZ(j)]        = v0;
        Y[SWZ(j +  512)] = v1;
        Y[SWZ(j + 1024)] = v2;
        Y[SWZ(j + 1536)] = v3;
    }
    if (xnext){
#pragma unroll
        for (int r = 0; r < 8; ++r) pre[r] = xnext[t + 256*r];
    }
    __syncthreads();                                   // B4

    // s5: spectral (untangle, *H, mask, retangle) fused with inverse
    // radix-8 stage 1 (no twiddles): Y -> X.  All scale factors deferred
    // to the final 1/8192.
    {
        float2 v[8];
#pragma unroll
        for (int r = 0; r < 8; ++r){
            const int k  = t + 256*r;
            const int kk = (r < 4) ? k : 2048 - k;     // bin in [0,1024]
            float2 zk = Y[SWZ(kk)];
            float2 zm = Y[SWZ((2048 - kk) & 2047)];    // kk=0 aliases (overridden)
            float2 w  = twq[TWPHYS(kk & 1023)];
            float2 A  = make_float2(zk.x + zm.x, zk.y - zm.y);   // 2*A
            float2 B  = make_float2(zk.x - zm.x, zk.y + zm.y);   // 2*B
            float2 wB = cmul(w, B);
            float2 Xc = make_float2(A.x + wB.y, A.y - wB.x);     // 2*X[kk]
            float2 vr = (r < 4) ? cmul(Xc, G[r]) : cmul_conja(Xc, G[r]);
            if (t == 0){
                if (r == 0){ float Y0 = (zk.x + zk.y) * G[0].x; vr = make_float2(Y0, Y0); }
                if (r == 4){ vr = make_float2(0.f, 0.f); }       // masked Nyquist-of-half bin
            }
            v[r] = vr;
        }
        fft8<1>(v);
        const int idxD = t << 3;
#pragma unroll
        for (int r = 0; r < 8; ++r) X[SWZ(idxD + r)] = v[r];
    }
    __syncthreads();                                   // B5
    stage8<1,8 >(X, Y, twq, t);  __syncthreads();      // B6
    stage8<1,64>(Y, X, twq, t);  __syncthreads();      // B7

    // s8: inverse radix-4 (Ns=512) fused with scale + bias + store, read X
    const float inv = (1.0f/8192.0f);
#pragma unroll
    for (int h = 0; h < 2; ++h){
        const int j = t + 256*h;
        float2 w1 = twq[TWPHYS(2*j)]; w1.y = -w1.y;
        float2 w2 = cmul(w1, w1);
        float2 w3 = cmul(w2, w1);
        float2 v0 = X[SWZ(j)];
        float2 v1 = cmul(X[SWZ(j +  512)], w1);
        float2 v2 = cmul(X[SWZ(j + 1024)], w2);
        float2 v3 = cmul(X[SWZ(j + 1536)], w3);
        fft4<1>(v0,v1,v2,v3);
        float2 vv[4] = {v0,v1,v2,v3};
#pragma unroll
        for (int r = 0; r < 4; ++r){
            const int mo = j + 512*r;
            float2 b = br2[mo];
            yr2[mo] = make_float2(fmaf(vv[r].x, inv, b.x), fmaf(vv[r].y, inv, b.y));
        }
    }
    // no trailing barrier: next row's s1 writes the OTHER buffer (parity),
    // and its first same-buffer write (s2) is behind that row's B1.
}

// NOTE: no min-waves clause. R5's __launch_bounds__(256,4) capped the
// allocator at 64 VGPR (< the ~120-reg live set incl. pre[8]+G[8]) ->
// scratch spills: FETCH 66->382 MB, WRITE 131->459 MB, dur 120->245 us.
extern "C" __global__ void __launch_bounds__(THREADS)
rfft_circ_kernel(const float* __restrict__ x,
                 const float* __restrict__ Hr,
                 const float* __restrict__ Hi,
                 const float* __restrict__ bias,
                 float* __restrict__ out)
{
    __shared__ float2 bufA[M];
    __shared__ float2 bufB[M];
    __shared__ float2 twq[1024];   // e^{-2pi i k/4096}, k<1024, phys-swizzled

    const int t = threadIdx.x;
    const size_t row0 = (size_t)blockIdx.x * ROWS_PER_WG;
    const float2* xr0 = (const float2*)(x + row0 * NFEAT);

    // Prefetch row 0 BEFORE the table build (sincos hides the HBM latency)
    float2 pre[8];
#pragma unroll
    for (int r = 0; r < 8; ++r) pre[r] = xr0[t + 256*r];

    for (int i = t; i < 1024; i += THREADS){
        float s, c;
        sincosf(-6.2831853071795864769f * (float)i * (1.0f/4096.0f), &s, &c);
        twq[TWPHYS(i)] = make_float2(c, s);
    }
    __syncthreads();

    // Row-invariant spectral factors: G[r] = H*f1 (k<1024) or conj(H)*f2.
    float2 G[8];
#pragma unroll
    for (int r = 0; r < 8; ++r){
        const int k  = t + 256*r;
        const int kk = ((r < 4) ? k : 2048 - k) & 1023;
        float2 w = twq[TWPHYS(kk)];
        float2 H = make_float2(Hr[kk], Hi[kk]);
        if (r < 4) G[r] = cmul(H, make_float2(1.f + w.y, w.x));
        else       G[r] = cmul(make_float2(H.x, -H.y), make_float2(1.f - w.y, w.x));
    }
    if (t == 0){ G[0] = make_float2(2.f*Hr[0], 0.f); G[4] = make_float2(0.f, 0.f); }

    const float2* br2 = (const float2*)bias;

#pragma unroll 1
    for (int rp = 0; rp < ROWS_PER_WG; rp += 2){
        {
            const int rr = rp;
            float2* yr2 = (float2*)(out + (row0 + rr) * NFEAT);
            const float2* xn = (rr + 1 < ROWS_PER_WG) ? xr0 + (size_t)(rr+1)*(NFEAT/2) : nullptr;
            row_body(bufA, bufB, twq, pre, G, xn, br2, yr2, t);
        }
        {
            const int rr = rp + 1;
            float2* yr2 = (float2*)(out + (row0 + rr) * NFEAT);
            const float2* xn = (rr + 1 < ROWS_PER_WG) ? xr0 + (size_t)(rr+1)*(NFEAT/2) : nullptr;
            row_body(bufB, bufA, twq, pre, G, xn, br2, yr2, t);
        }
    }
}

extern "C" void kernel_launch(void* const* d_in, const int* in_sizes, int n_in,
                              void* d_out, int out_size, void* d_ws, size_t ws_size,
                              hipStream_t stream) {
    const float* x    = (const float*)d_in[0];
    const float* Hr   = (const float*)d_in[1];
    const float* Hi   = (const float*)d_in[2];
    const float* bias = (const float*)d_in[3];
    float* out        = (float*)d_out;

    const int n_rows = in_sizes[0] / NFEAT;   // 8192 at reference shape
    dim3 grid(n_rows / ROWS_PER_WG), block(THREADS);
    hipLaunchKernelGGL(rfft_circ_kernel, grid, block, 0, stream,
                       x, Hr, Hi, bias, out);
}

// Round 7
// 248.289 us; speedup vs baseline: 1.5888x; 1.0138x over previous
//
#include <hip/hip_runtime.h>
#include <math.h>

#define NFEAT 4096
#define M     2048
#define THREADS 256
#define ROWS_PER_WG 8

// Packed-capable 2-float vector: lets LLVM select v_pk_{add,mul,fma}_f32
// (VOP3P, gfx90a+) instead of scalar pairs.
typedef float v2 __attribute__((ext_vector_type(2)));

// Data-buffer swizzle: bijective on [0,2048); lane-contiguous reads stay
// conflict-free, strided Stockham writes spread across bank pairs.
#define SWZ(i) ((i) ^ (((i) >> 4) & 15))
// Twiddle-table physical swizzle: spreads multiples-of-64 gather indices.
#define TWPHYS(e) ((e) ^ (((e) >> 4) & 15))

__device__ __forceinline__ v2 cmul(v2 a, v2 b){
    v2 axx = __builtin_shufflevector(a, a, 0, 0);
    v2 ayy = __builtin_shufflevector(a, a, 1, 1);
    v2 byx = __builtin_shufflevector(b, b, 1, 0);
    v2 t   = ayy * byx;
    t = (v2){-t.x, t.y};          // fold target: neg_lo on the fma
    return axx * b + t;
}
// conj(a)*b
__device__ __forceinline__ v2 cmul_conja(v2 a, v2 b){
    v2 axx = __builtin_shufflevector(a, a, 0, 0);
    v2 ayy = __builtin_shufflevector(a, a, 1, 1);
    v2 byx = __builtin_shufflevector(b, b, 1, 0);
    v2 t   = ayy * byx;
    t = (v2){t.x, -t.y};
    return axx * b + t;
}

template<int SIGN>
__device__ __forceinline__ void fft4(v2& a0, v2& a1, v2& a2, v2& a3){
    v2 t0 = a0 + a2, t1 = a0 - a2;
    v2 t2 = a1 + a3, t3 = a1 - a3;
    v2 r3 = (SIGN < 0) ? (v2){t3.y, -t3.x} : (v2){-t3.y, t3.x};
    a0 = t0 + t2; a2 = t0 - t2;
    a1 = t1 + r3; a3 = t1 - r3;
}

template<int SIGN>
__device__ __forceinline__ void fft8(v2 v[8]){
    const float C = 0.70710678118654752440f;
    v2 e0=v[0], e1=v[2], e2=v[4], e3=v[6];
    v2 o0=v[1], o1=v[3], o2=v[5], o3=v[7];
    fft4<SIGN>(e0,e1,e2,e3);
    fft4<SIGN>(o0,o1,o2,o3);
    v2 w1 = (v2){ C, (SIGN<0) ? -C : C};
    v2 w3 = (v2){-C, (SIGN<0) ? -C : C};
    v2 o1w = cmul(o1, w1);
    v2 o2w = (SIGN<0) ? (v2){o2.y, -o2.x} : (v2){-o2.y, o2.x};
    v2 o3w = cmul(o3, w3);
    v[0]=e0+o0;  v[4]=e0-o0;
    v[1]=e1+o1w; v[5]=e1-o1w;
    v[2]=e2+o2w; v[6]=e2-o2w;
    v[3]=e3+o3w; v[7]=e3-o3w;
}

// Radix-8 Stockham stage (NS in {8,64}): ONE twiddle table load per
// butterfly (even quarter-4096 index, no fixups) + power-chain cmuls.
template<int SIGN, int NS>
__device__ __forceinline__ void stage8(const v2* __restrict__ src, v2* __restrict__ dst,
                                       const v2* __restrict__ twq, int j){
    const int m  = j & (NS - 1);
    v2 v[8];
#pragma unroll
    for (int r = 0; r < 8; ++r) v[r] = src[SWZ(j + 256*r)];
    {
        // w2048^tb, tb = m*M/(8*NS)  ->  twq index 2*tb = m*M/(4*NS) < 1024
        v2 wb = twq[TWPHYS(m * (M / (NS * 4)))];
        if (SIGN > 0) wb.y = -wb.y;
        v2 w = wb;
        v[1] = cmul(v[1], w);
#pragma unroll
        for (int r = 2; r < 8; ++r){ w = cmul(w, wb); v[r] = cmul(v[r], w); }
    }
    fft8<SIGN>(v);
    const int idxD = ((j - m) << 3) + m;
#pragma unroll
    for (int r = 0; r < 8; ++r) dst[SWZ(idxD + NS*r)] = v[r];
}

// One full row. X = first scratch buffer written this row, Y = the other;
// caller alternates per row parity so no trailing barrier is needed.
__device__ __forceinline__ void row_body(v2* __restrict__ X, v2* __restrict__ Y,
                                         const v2* __restrict__ twq,
                                         v2 (&pre)[8], const v2 (&G)[8],
                                         const v2* __restrict__ xnext,
                                         const v2* __restrict__ br2,
                                         v2* __restrict__ yr2, int t)
{
    // s1: forward radix-8 (Ns=1) on prefetched regs -> X
    {
        v2 v[8];
#pragma unroll
        for (int r = 0; r < 8; ++r) v[r] = pre[r];
        fft8<-1>(v);
        const int idxD = t << 3;
#pragma unroll
        for (int r = 0; r < 8; ++r) X[SWZ(idxD + r)] = v[r];
    }
    __syncthreads();                                   // B1
    stage8<-1,8 >(X, Y, twq, t);  __syncthreads();     // B2
    stage8<-1,64>(Y, X, twq, t);  __syncthreads();     // B3

    // s4: forward radix-4 (Ns=512): X -> Y, then prefetch next row
#pragma unroll
    for (int h = 0; h < 2; ++h){
        const int j = t + 256*h;
        v2 w1 = twq[TWPHYS(2*j)];
        v2 w2 = cmul(w1, w1);
        v2 w3 = cmul(w2, w1);
        v2 v0 = X[SWZ(j)];
        v2 v1 = cmul(X[SWZ(j +  512)], w1);
        v2 v2_ = cmul(X[SWZ(j + 1024)], w2);
        v2 v3 = cmul(X[SWZ(j + 1536)], w3);
        fft4<-1>(v0,v1,v2_,v3);
        Y[SWZ(j)]        = v0;
        Y[SWZ(j +  512)] = v1;
        Y[SWZ(j + 1024)] = v2_;
        Y[SWZ(j + 1536)] = v3;
    }
    if (xnext){
#pragma unroll
        for (int r = 0; r < 8; ++r) pre[r] = xnext[t + 256*r];
    }
    __syncthreads();                                   // B4

    // s5: spectral (untangle, *H, mask, retangle) fused with inverse
    // radix-8 stage 1 (no twiddles): Y -> X.  Scales deferred to 1/8192.
    {
        v2 v[8];
#pragma unroll
        for (int r = 0; r < 8; ++r){
            const int k  = t + 256*r;
            const int kk = (r < 4) ? k : 2048 - k;     // bin in [0,1024]
            v2 zk = Y[SWZ(kk)];
            v2 zm = Y[SWZ((2048 - kk) & 2047)];        // kk=0 aliases (overridden)
            v2 w  = twq[TWPHYS(kk & 1023)];
            v2 A  = (v2){zk.x + zm.x, zk.y - zm.y};    // 2*A
            v2 B  = (v2){zk.x - zm.x, zk.y + zm.y};    // 2*B
            v2 wB = cmul(w, B);
            v2 Xc = (v2){A.x + wB.y, A.y - wB.x};      // 2*X[kk]
            v2 vr = (r < 4) ? cmul(Xc, G[r]) : cmul_conja(Xc, G[r]);
            if (t == 0){
                if (r == 0){ float Y0 = (zk.x + zk.y) * G[0].x; vr = (v2){Y0, Y0}; }
                if (r == 4){ vr = (v2){0.f, 0.f}; }
            }
            v[r] = vr;
        }
        fft8<1>(v);
        const int idxD = t << 3;
#pragma unroll
        for (int r = 0; r < 8; ++r) X[SWZ(idxD + r)] = v[r];
    }
    __syncthreads();                                   // B5
    stage8<1,8 >(X, Y, twq, t);  __syncthreads();      // B6
    stage8<1,64>(Y, X, twq, t);  __syncthreads();      // B7

    // s8: inverse radix-4 (Ns=512) fused with scale + bias + store, read X
    const float inv = (1.0f/8192.0f);
#pragma unroll
    for (int h = 0; h < 2; ++h){
        const int j = t + 256*h;
        v2 w1 = twq[TWPHYS(2*j)]; w1.y = -w1.y;
        v2 w2 = cmul(w1, w1);
        v2 w3 = cmul(w2, w1);
        v2 v0 = X[SWZ(j)];
        v2 v1 = cmul(X[SWZ(j +  512)], w1);
        v2 v2_ = cmul(X[SWZ(j + 1024)], w2);
        v2 v3 = cmul(X[SWZ(j + 1536)], w3);
        fft4<1>(v0,v1,v2_,v3);
        v2 vv[4] = {v0,v1,v2_,v3};
#pragma unroll
        for (int r = 0; r < 4; ++r){
            const int mo = j + 512*r;
            yr2[mo] = br2[mo] + vv[r] * inv;
        }
    }
    // no trailing barrier: next row's s1 writes the OTHER buffer (parity),
    // and its first same-buffer write (s2) is behind that row's B1.
}

// NOTE: no min-waves clause — R5 showed __launch_bounds__(256,4) caps the
// allocator at 64 VGPR (< live set) -> massive scratch spills.
extern "C" __global__ void __launch_bounds__(THREADS)
rfft_circ_kernel(const float* __restrict__ x,
                 const float* __restrict__ Hr,
                 const float* __restrict__ Hi,
                 const float* __restrict__ bias,
                 float* __restrict__ out)
{
    __shared__ v2 bufA[M];
    __shared__ v2 bufB[M];
    __shared__ v2 twq[1024];   // e^{-2pi i k/4096}, k<1024, phys-swizzled

    const int t = threadIdx.x;
    const size_t row0 = (size_t)blockIdx.x * ROWS_PER_WG;
    const v2* xr0 = (const v2*)(x + row0 * NFEAT);

    // Prefetch row 0 BEFORE the table build (sincos hides the HBM latency)
    v2 pre[8];
#pragma unroll
    for (int r = 0; r < 8; ++r) pre[r] = xr0[t + 256*r];

    for (int i = t; i < 1024; i += THREADS){
        float s, c;
        sincosf(-6.2831853071795864769f * (float)i * (1.0f/4096.0f), &s, &c);
        twq[TWPHYS(i)] = (v2){c, s};
    }
    __syncthreads();

    // Row-invariant spectral factors: G[r] = H*f1 (k<1024) or conj(H)*f2.
    v2 G[8];
#pragma unroll
    for (int r = 0; r < 8; ++r){
        const int k  = t + 256*r;
        const int kk = ((r < 4) ? k : 2048 - k) & 1023;
        v2 w = twq[TWPHYS(kk)];
        v2 H = (v2){Hr[kk], Hi[kk]};
        if (r < 4) G[r] = cmul(H, (v2){1.f + w.y, w.x});
        else       G[r] = cmul((v2){H.x, -H.y}, (v2){1.f - w.y, w.x});
    }
    if (t == 0){ G[0] = (v2){2.f*Hr[0], 0.f}; G[4] = (v2){0.f, 0.f}; }

    const v2* br2 = (const v2*)bias;

#pragma unroll 1
    for (int rp = 0; rp < ROWS_PER_WG; rp += 2){
        {
            const int rr = rp;
            v2* yr2 = (v2*)(out + (row0 + rr) * NFEAT);
            const v2* xn = (rr + 1 < ROWS_PER_WG) ? xr0 + (size_t)(rr+1)*(NFEAT/2) : nullptr;
            row_body(bufA, bufB, twq, pre, G, xn, br2, yr2, t);
        }
        {
            const int rr = rp + 1;
            v2* yr2 = (v2*)(out + (row0 + rr) * NFEAT);
            const v2* xn = (rr + 1 < ROWS_PER_WG) ? xr0 + (size_t)(rr+1)*(NFEAT/2) : nullptr;
            row_body(bufB, bufA, twq, pre, G, xn, br2, yr2, t);
        }
    }
}

extern "C" void kernel_launch(void* const* d_in, const int* in_sizes, int n_in,
                              void* d_out, int out_size, void* d_ws, size_t ws_size,
                              hipStream_t stream) {
    const float* x    = (const float*)d_in[0];
    const float* Hr   = (const float*)d_in[1];
    const float* Hi   = (const float*)d_in[2];
    const float* bias = (const float*)d_in[3];
    float* out        = (float*)d_out;

    const int n_rows = in_sizes[0] / NFEAT;   // 8192 at reference shape
    dim3 grid(n_rows / ROWS_PER_WG), block(THREADS);
    hipLaunchKernelGGL(rfft_circ_kernel, grid, block, 0, stream,
                       x, Hr, Hi, bias, out);
}